// Round 14
// baseline (71.776 us; speedup 1.0000x reference)
//
#include <hip/hip_runtime.h>
#include <hip/hip_bf16.h>

#define T_TOKENS 2048
#define DIM 256
#define NLEV 8
#define MAXU 320   // max (node, 256-chunk) units: sum ceil(cnt/256) <= 263

using bf16x8 = __attribute__((ext_vector_type(8))) short;
using f32x4  = __attribute__((ext_vector_type(4))) float;

__device__ __forceinline__ unsigned short f2bf(float f) {
    union { float f; unsigned u; } v; v.f = f;
    unsigned r = v.u + 0x7FFFu + ((v.u >> 16) & 1u);   // RNE
    return (unsigned short)(r >> 16);
}

// ---------------- Kernel 1: routing (exact fp32) + x -> bf16 conversion ----------------
__global__ __launch_bounds__(256) void route_kernel(
    const float* __restrict__ x, const float* __restrict__ w1s,
    const float* __restrict__ b1s,
    float* __restrict__ pw,            // [T][8]
    int*   __restrict__ pc,            // [T] pathcode in [256,511]
    unsigned short* __restrict__ xbf)  // [T][256] bf16
{
    int wave = threadIdx.x >> 6;
    int lane = threadIdx.x & 63;
    int t = blockIdx.x * 4 + wave;    // grid = 512 -> t < 2048

    const float4 xv = *reinterpret_cast<const float4*>(x + (size_t)t * DIM + lane * 4);

    ushort4 xb;
    xb.x = f2bf(xv.x); xb.y = f2bf(xv.y); xb.z = f2bf(xv.z); xb.w = f2bf(xv.w);
    *reinterpret_cast<ushort4*>(xbf + (size_t)t * DIM + lane * 4) = xb;

    int p = 1;
    float keep = 0.0f;
    #pragma unroll
    for (int lvl = 0; lvl < NLEV; ++lvl) {
        int node = p - 1;
        const float4 wv = *reinterpret_cast<const float4*>(w1s + (size_t)node * DIM + lane * 4);
        float s = xv.x * wv.x + xv.y * wv.y + xv.z * wv.z + xv.w * wv.w;
        #pragma unroll
        for (int off = 32; off; off >>= 1) s += __shfl_xor(s, off);
        float score = s + b1s[node];
        float a = fabsf(score);
        float g = a * 0.5f * (1.0f + erff(a * 0.70710678118654752f));  // exact GELU
        if (lane == lvl) keep = g;
        int choice = (score > 0.0f) ? 1 : 0;   // sign(0)->choice 0 matches ref
        p = 2 * p + choice;
    }
    if (lane < NLEV) pw[(size_t)t * NLEV + lane] = keep;
    if (lane == 0) pc[t] = p;
}

// ---------------- Kernel 2: counting sort + 256-chunk unit enumeration (1 block) ----------------
__global__ __launch_bounds__(256) void sort_kernel(
    const int* __restrict__ pc,
    int* __restrict__ order, unsigned* __restrict__ units, int* __restrict__ ucount)
{
    __shared__ int hist[256];
    __shared__ int offs[256];
    __shared__ int cums[257];
    __shared__ int wpart[4];
    int tid = threadIdx.x;
    hist[tid] = 0;
    __syncthreads();

    int myPc[8];
    #pragma unroll
    for (int i = 0; i < 8; ++i) {
        int t = tid * 8 + i;
        myPc[i] = pc[t];
        atomicAdd(&hist[myPc[i] - 256], 1);
    }
    __syncthreads();

    if (tid < 64) {
        int lane = tid;
        int v0 = hist[lane * 4 + 0], v1 = hist[lane * 4 + 1];
        int v2 = hist[lane * 4 + 2], v3 = hist[lane * 4 + 3];
        int sum = v0 + v1 + v2 + v3;
        int scan = sum;
        #pragma unroll
        for (int off = 1; off < 64; off <<= 1) {
            int n = __shfl_up(scan, off);
            if (lane >= off) scan += n;
        }
        int excl = scan - sum;
        offs[lane * 4 + 0] = excl;
        offs[lane * 4 + 1] = excl + v0;
        offs[lane * 4 + 2] = excl + v0 + v1;
        offs[lane * 4 + 3] = excl + v0 + v1 + v2;
    }
    __syncthreads();

    cums[tid] = offs[tid];
    if (tid == 0) cums[256] = T_TOKENS;
    __syncthreads();

    #pragma unroll
    for (int i = 0; i < 8; ++i) {
        int t = tid * 8 + i;
        int bin = myPc[i] - 256;
        int pos = atomicAdd(&offs[bin], 1);
        order[pos] = t;
    }

    // ---- unit enumeration: thread tid = node id; chunks of <=256 tokens ----
    int nch = 0, s = 0, e = 0, l = 0;
    if (tid < 255) {
        int q = tid + 1;
        l = 31 - __clz(q);
        int shift = 8 - l;
        int lo = (q << shift) - 256;
        int hi = ((q + 1) << shift) - 256;
        s = cums[lo];
        e = cums[hi];
        nch = (e - s + 255) >> 8;
    }
    int lane = tid & 63, w = tid >> 6;
    int scan = nch;
    #pragma unroll
    for (int off = 1; off < 64; off <<= 1) {
        int n = __shfl_up(scan, off);
        if (lane >= off) scan += n;
    }
    if (lane == 63) wpart[w] = scan;
    __syncthreads();
    int pre = 0;
    for (int k = 0; k < w; ++k) pre += wpart[k];
    int base = pre + scan - nch;
    for (int j = 0; j < nch; ++j) {
        int st = s + j * 256;
        int c = e - st; if (c > 256) c = 256;
        units[base + j] = (unsigned)tid | ((unsigned)l << 8) |
                          ((unsigned)st << 11) | ((unsigned)(c - 1) << 22);
    }
    if (tid == 255) *ucount = pre + scan;
}

// ---------------- Kernel 3: wave = (unit, 32-col strip); B in regs, read-once w2 ----------------
// grid = 2560 x 64 threads. XCD-chunked swizzle keeps same-node strips on one XCD.
// Each w2 element is loaded+converted by exactly ONE wave. No LDS, no barriers.
__global__ __launch_bounds__(64, 4) void out_kernel(
    const unsigned short* __restrict__ xbf, const float* __restrict__ w2s,
    const float* __restrict__ b2s, const float* __restrict__ pw,
    const int* __restrict__ order, const unsigned* __restrict__ units,
    const int* __restrict__ ucount, float* __restrict__ lvlbuf)
{
    int bid = blockIdx.x;
    int L = (bid & 7) * MAXU + (bid >> 3);   // bijective: 2560 = 8 * MAXU
    int u = L >> 3, strip = L & 7;
    if (u >= *ucount) return;
    unsigned d = units[u];
    int node  = (int)(d & 255u);
    int lvl   = (int)((d >> 8) & 7u);
    int start = (int)((d >> 11) & 2047u);
    int cnt   = (int)((d >> 22) & 255u) + 1;

    int lane = threadIdx.x;
    int l15 = lane & 15, kg = lane >> 4;
    int colbase = strip * 32;

    // preload sorted-order rows for up to 256 tokens (4 regs)
    int i1 = 64 + lane, i2 = 128 + lane, i3 = 192 + lane;
    int ord0 = order[start + (lane < cnt ? lane : cnt - 1)];
    int ord1 = order[start + (i1 < cnt ? i1 : cnt - 1)];
    int ord2 = order[start + (i2 < cnt ? i2 : cnt - 1)];
    int ord3 = order[start + (i3 < cnt ? i3 : cnt - 1)];

    // B fragments: bfr[nb][ks][i] = w2[node][ks*32+kg*8+i][colbase + nb*16 + l15]
    const float* w2n = w2s + ((size_t)node << 16) + colbase + l15;
    bf16x8 bfr0[8], bfr1[8];
    #pragma unroll
    for (int ks = 0; ks < 8; ++ks) {
        const float* bp = w2n + (size_t)(ks * 32 + kg * 8) * DIM;
        bf16x8 v0, v1;
        #pragma unroll
        for (int i = 0; i < 8; ++i) {
            v0[i] = (short)f2bf(bp[(size_t)i * DIM]);
            v1[i] = (short)f2bf(bp[(size_t)i * DIM + 16]);
        }
        bfr0[ks] = v0;
        bfr1[ks] = v1;
    }

    float bias0 = b2s[((size_t)node << 8) + colbase + l15];
    float bias1 = b2s[((size_t)node << 8) + colbase + 16 + l15];
    float* dst = lvlbuf + ((size_t)lvl << 19);   // 2048*256 per level
    int nmt = (cnt + 15) >> 4;

    for (int m = 0; m < nmt; ++m) {
        // token for row l15 of m-tile via register shuffle (no memory load)
        int sel = m >> 2;
        int vsrc = (sel == 0) ? ord0 : (sel == 1) ? ord1 : (sel == 2) ? ord2 : ord3;
        int tk = __shfl(vsrc, (m & 3) * 16 + l15);

        const unsigned short* xp = xbf + ((size_t)tk << 8) + kg * 8;
        bf16x8 a[8];
        #pragma unroll
        for (int ks = 0; ks < 8; ++ks)
            a[ks] = *reinterpret_cast<const bf16x8*>(xp + ks * 32);

        f32x4 acc0 = {0.f, 0.f, 0.f, 0.f};
        f32x4 acc1 = {0.f, 0.f, 0.f, 0.f};
        #pragma unroll
        for (int ks = 0; ks < 8; ++ks) {
            acc0 = __builtin_amdgcn_mfma_f32_16x16x32_bf16(a[ks], bfr0[ks], acc0, 0, 0, 0);
            acc1 = __builtin_amdgcn_mfma_f32_16x16x32_bf16(a[ks], bfr1[ks], acc1, 0, 0, 0);
        }

        #pragma unroll
        for (int j = 0; j < 4; ++j) {
            int r = m * 16 + kg * 4 + j;
            if (r < cnt) {
                int t = __shfl(tk, kg * 4 + j);
                float w = pw[(size_t)t * NLEV + lvl];
                dst[((size_t)t << 8) + colbase + l15]      = w * (acc0[j] + bias0);
                dst[((size_t)t << 8) + colbase + 16 + l15] = w * (acc1[j] + bias1);
            }
        }
    }
}

// ---------------- Kernel 4: reduce 8 level-buffers -> out ----------------
__global__ __launch_bounds__(256) void reduce_kernel(
    const float* __restrict__ lvlbuf, float* __restrict__ out)
{
    int idx = blockIdx.x * 256 + threadIdx.x;          // float4 index, < 131072
    const float4* lb = reinterpret_cast<const float4*>(lvlbuf);
    float4 s = lb[idx];
    #pragma unroll
    for (int l = 1; l < NLEV; ++l) {
        float4 v = lb[(size_t)l * 131072 + idx];
        s.x += v.x; s.y += v.y; s.z += v.z; s.w += v.w;
    }
    reinterpret_cast<float4*>(out)[idx] = s;
}

extern "C" void kernel_launch(void* const* d_in, const int* in_sizes, int n_in,
                              void* d_out, int out_size, void* d_ws, size_t ws_size,
                              hipStream_t stream) {
    const float* x   = (const float*)d_in[0];
    const float* w1s = (const float*)d_in[1];
    const float* b1s = (const float*)d_in[2];
    const float* w2s = (const float*)d_in[3];
    const float* b2s = (const float*)d_in[4];
    float* out = (float*)d_out;

    // workspace layout
    float* pw            = (float*)d_ws;                          // 64 KB
    int* pc              = (int*)(pw + T_TOKENS * NLEV);          // 8 KB
    int* order           = pc + T_TOKENS;                         // 8 KB
    unsigned* units      = (unsigned*)(order + T_TOKENS);         // 2 KB
    int* ucount          = (int*)(units + 512);                   // 4 B
    unsigned short* xbf  = (unsigned short*)((char*)d_ws + (256 << 10));  // 1 MB
    float* lvlbuf        = (float*)((char*)d_ws + (2 << 20));     // 16 MB

    route_kernel<<<T_TOKENS / 4, 256, 0, stream>>>(x, w1s, b1s, pw, pc, xbf);
    sort_kernel<<<1, 256, 0, stream>>>(pc, order, units, ucount);
    out_kernel<<<8 * MAXU, 64, 0, stream>>>(xbf, w2s, b2s, pw, order, units, ucount, lvlbuf);
    reduce_kernel<<<512, 256, 0, stream>>>(lvlbuf, out);
}

// Round 15
// 45.377 us; speedup vs baseline: 1.5818x; 1.5818x over previous
//
#include <hip/hip_runtime.h>
#include <hip/hip_bf16.h>

#define T_TOKENS 2048
#define DIM 256
#define NLEV 8
#define MAXU 512

using bf16x8 = __attribute__((ext_vector_type(8))) short;
using f32x4  = __attribute__((ext_vector_type(4))) float;

__device__ __forceinline__ unsigned short f2bf(float f) {
    union { float f; unsigned u; } v; v.f = f;
    unsigned r = v.u + 0x7FFFu + ((v.u >> 16) & 1u);   // RNE
    return (unsigned short)(r >> 16);
}

// ---------------- Kernel 1: routing (exact fp32) + x -> bf16 conversion ----------------
__global__ __launch_bounds__(256) void route_kernel(
    const float* __restrict__ x, const float* __restrict__ w1s,
    const float* __restrict__ b1s,
    float* __restrict__ pw, int* __restrict__ pc,
    unsigned short* __restrict__ xbf)
{
    int wave = threadIdx.x >> 6;
    int lane = threadIdx.x & 63;
    int t = blockIdx.x * 4 + wave;    // grid = 512 -> t < 2048

    const float4 xv = *reinterpret_cast<const float4*>(x + (size_t)t * DIM + lane * 4);

    ushort4 xb;
    xb.x = f2bf(xv.x); xb.y = f2bf(xv.y); xb.z = f2bf(xv.z); xb.w = f2bf(xv.w);
    *reinterpret_cast<ushort4*>(xbf + (size_t)t * DIM + lane * 4) = xb;

    int p = 1;
    float keep = 0.0f;
    #pragma unroll
    for (int lvl = 0; lvl < NLEV; ++lvl) {
        int node = p - 1;
        const float4 wv = *reinterpret_cast<const float4*>(w1s + (size_t)node * DIM + lane * 4);
        float s = xv.x * wv.x + xv.y * wv.y + xv.z * wv.z + xv.w * wv.w;
        #pragma unroll
        for (int off = 32; off; off >>= 1) s += __shfl_xor(s, off);
        float score = s + b1s[node];
        float a = fabsf(score);
        float g = a * 0.5f * (1.0f + erff(a * 0.70710678118654752f));  // exact GELU
        if (lane == lvl) keep = g;
        int choice = (score > 0.0f) ? 1 : 0;   // sign(0)->choice 0 matches ref
        p = 2 * p + choice;
    }
    if (lane < NLEV) pw[(size_t)t * NLEV + lane] = keep;
    if (lane == 0) pc[t] = p;
}

// ---------------- Kernel 2: counting sort + 64-chunk unit enumeration (1 block) ----------------
__global__ __launch_bounds__(256) void sort_kernel(
    const int* __restrict__ pc,
    int* __restrict__ order, unsigned* __restrict__ units, int* __restrict__ ucount)
{
    __shared__ int hist[256];
    __shared__ int offs[256];
    __shared__ int cums[257];
    __shared__ int wpart[4];
    int tid = threadIdx.x;
    hist[tid] = 0;
    __syncthreads();

    int myPc[8];
    #pragma unroll
    for (int i = 0; i < 8; ++i) {
        int t = tid * 8 + i;
        myPc[i] = pc[t];
        atomicAdd(&hist[myPc[i] - 256], 1);
    }
    __syncthreads();

    if (tid < 64) {
        int lane = tid;
        int v0 = hist[lane * 4 + 0], v1 = hist[lane * 4 + 1];
        int v2 = hist[lane * 4 + 2], v3 = hist[lane * 4 + 3];
        int sum = v0 + v1 + v2 + v3;
        int scan = sum;
        #pragma unroll
        for (int off = 1; off < 64; off <<= 1) {
            int n = __shfl_up(scan, off);
            if (lane >= off) scan += n;
        }
        int excl = scan - sum;
        offs[lane * 4 + 0] = excl;
        offs[lane * 4 + 1] = excl + v0;
        offs[lane * 4 + 2] = excl + v0 + v1;
        offs[lane * 4 + 3] = excl + v0 + v1 + v2;
    }
    __syncthreads();

    cums[tid] = offs[tid];
    if (tid == 0) cums[256] = T_TOKENS;
    __syncthreads();

    #pragma unroll
    for (int i = 0; i < 8; ++i) {
        int t = tid * 8 + i;
        int bin = myPc[i] - 256;
        int pos = atomicAdd(&offs[bin], 1);
        order[pos] = t;
    }

    int nch = 0, s = 0, e = 0, l = 0;
    if (tid < 255) {
        int q = tid + 1;
        l = 31 - __clz(q);
        int shift = 8 - l;
        int lo = (q << shift) - 256;
        int hi = ((q + 1) << shift) - 256;
        s = cums[lo];
        e = cums[hi];
        nch = (e - s + 63) >> 6;
    }
    int lane = tid & 63, w = tid >> 6;
    int scan = nch;
    #pragma unroll
    for (int off = 1; off < 64; off <<= 1) {
        int n = __shfl_up(scan, off);
        if (lane >= off) scan += n;
    }
    if (lane == 63) wpart[w] = scan;
    __syncthreads();
    int pre = 0;
    for (int k = 0; k < w; ++k) pre += wpart[k];
    int base = pre + scan - nch;
    for (int j = 0; j < nch; ++j) {
        int st = s + j * 64;
        int c = e - st; if (c > 64) c = 64;
        units[base + j] = (unsigned)tid | ((unsigned)l << 8) |
                          ((unsigned)st << 11) | ((unsigned)c << 22);
    }
    if (tid == 255) *ucount = pre + scan;
}

// ---------------- Kernel 3: async-staged per-unit GEMM (T3/T4: global_load_lds + counted vmcnt) ----------------
// Block = (unit<=64 tok, col-half 128). 4 waves, wave wv -> cols ch*128 + wv*32..+31.
// B: fp32 32k x 128c panels DMA'd to LDS via global_load_lds, 2-deep, vmcnt(4) never
// drained to 0 mid-loop; raw s_barrier (no vmcnt(0) drain). A: direct from L2-hot xbf.
// LDS = 32 KB only -> 4+ blocks/CU. fp32->bf16 convert on LDS read.
__global__ __launch_bounds__(256, 4) void out_kernel(
    const unsigned short* __restrict__ xbf, const float* __restrict__ w2s,
    const float* __restrict__ b2s, const float* __restrict__ pw,
    const int* __restrict__ order, const unsigned* __restrict__ units,
    const int* __restrict__ ucount, float* __restrict__ lvlbuf)
{
    __shared__ float Bs[2][32][128];   // 2 x 16 KiB, linear (global_load_lds dest)

    int u = blockIdx.x >> 1;
    if (u >= *ucount) return;          // uniform exit BEFORE any barrier
    unsigned d = units[u];
    int node  = (int)(d & 255u);
    int lvl   = (int)((d >> 8) & 7u);
    int start = (int)((d >> 11) & 2047u);
    int cnt   = (int)((d >> 22) & 127u);
    int ch = blockIdx.x & 1;

    int tid = threadIdx.x;
    int wv = tid >> 6, lane = tid & 63;
    int l15 = lane & 15, kg = lane >> 4;

    int tok[4];
    #pragma unroll
    for (int m = 0; m < 4; ++m) {
        int r = m * 16 + l15;
        tok[m] = order[start + (r < cnt ? r : cnt - 1)];
    }

    const float* w2n = w2s + ((size_t)node << 16) + ch * 128;
    int srow = wv * 8 + (lane >> 5);     // staging row within panel (+= i*2)
    int scol = (lane & 31) * 4;          // staging col (floats)

    // stage panel p (rows [p*32, p*32+32) x 128 cols fp32) into Bs[q]; 4 DMA ops/wave
    auto STAGE = [&](int p, int q) {
        #pragma unroll
        for (int i = 0; i < 4; ++i) {
            const float* src = w2n + (size_t)(p * 32 + srow + i * 2) * 256 + scol;
            float* dst = &Bs[q][wv * 8 + i * 2][0];   // wave-uniform base; HW adds lane*16
            __builtin_amdgcn_global_load_lds(
                (const __attribute__((address_space(1))) void*)src,
                (__attribute__((address_space(3))) void*)dst, 16, 0, 0);
        }
    };
    // A fragments for panel p: 4 x 16B loads from xbf (L2-hot)
    auto LOADA = [&](int p, bf16x8 (&a)[4]) {
        #pragma unroll
        for (int m = 0; m < 4; ++m)
            a[m] = *reinterpret_cast<const bf16x8*>(xbf + ((size_t)tok[m] << 8) + p * 32 + kg * 8);
    };

    f32x4 acc[4][2];
    #pragma unroll
    for (int m = 0; m < 4; ++m) {
        acc[m][0] = (f32x4){0.f, 0.f, 0.f, 0.f};
        acc[m][1] = (f32x4){0.f, 0.f, 0.f, 0.f};
    }

    auto COMPUTE = [&](int q, const bf16x8 (&a)[4]) {
        bf16x8 bf[2];
        #pragma unroll
        for (int nb = 0; nb < 2; ++nb) {
            bf16x8 v;
            #pragma unroll
            for (int i = 0; i < 8; ++i)
                v[i] = (short)f2bf(Bs[q][kg * 8 + i][wv * 32 + nb * 16 + l15]);
            bf[nb] = v;
        }
        #pragma unroll
        for (int m = 0; m < 4; ++m) if (m * 16 < cnt)
            #pragma unroll
            for (int nb = 0; nb < 2; ++nb)
                acc[m][nb] = __builtin_amdgcn_mfma_f32_16x16x32_bf16(a[m], bf[nb], acc[m][nb], 0, 0, 0);
    };

    bf16x8 aP[4], aQ[4];

    // prologue: S0, A0, S1 in flight (12 ops); vmcnt(4) retires S0+A0, leaves S1
    STAGE(0, 0);
    LOADA(0, aP);
    STAGE(1, 1);
    asm volatile("s_waitcnt vmcnt(4)" ::: "memory");
    __builtin_amdgcn_s_barrier();
    __builtin_amdgcn_sched_barrier(0);

    #pragma unroll
    for (int p = 0; p < 8; ++p) {
        if (p & 1) COMPUTE(1, aQ); else COMPUTE(0, aP);
        __builtin_amdgcn_s_barrier();          // all waves done reading Bs[p&1]
        if (p < 6) {
            if (p & 1) LOADA(p + 1, aP); else LOADA(p + 1, aQ);
            STAGE(p + 2, p & 1);               // overwrite just-consumed buffer
            // outstanding: S(p+1)4 + A(p+1)4 + S(p+2)4 -> keep only S(p+2) in flight
            asm volatile("s_waitcnt vmcnt(4)" ::: "memory");
        } else if (p == 6) {
            LOADA(7, aQ);
            asm volatile("s_waitcnt vmcnt(0)" ::: "memory");
        }
        __builtin_amdgcn_s_barrier();
        __builtin_amdgcn_sched_barrier(0);
    }

    // epilogue: lvlbuf[lvl][tok][col] = pw[tok][lvl] * (acc + bias)
    float bias[2];
    #pragma unroll
    for (int nb = 0; nb < 2; ++nb)
        bias[nb] = b2s[((size_t)node << 8) + ch * 128 + wv * 32 + nb * 16 + l15];

    float* dst = lvlbuf + ((size_t)lvl << 19);

    #pragma unroll
    for (int m = 0; m < 4; ++m) if (m * 16 < cnt) {
        #pragma unroll
        for (int j = 0; j < 4; ++j) {
            int r = m * 16 + kg * 4 + j;
            if (r < cnt) {
                int t = __shfl(tok[m], kg * 4 + j);
                float w = pw[(size_t)t * NLEV + lvl];
                #pragma unroll
                for (int nb = 0; nb < 2; ++nb)
                    dst[((size_t)t << 8) + ch * 128 + wv * 32 + nb * 16 + l15] =
                        w * (acc[m][nb][j] + bias[nb]);
            }
        }
    }
}

// ---------------- Kernel 4: reduce 8 level-buffers -> out ----------------
__global__ __launch_bounds__(256) void reduce_kernel(
    const float* __restrict__ lvlbuf, float* __restrict__ out)
{
    int idx = blockIdx.x * 256 + threadIdx.x;
    const float4* lb = reinterpret_cast<const float4*>(lvlbuf);
    float4 s = lb[idx];
    #pragma unroll
    for (int l = 1; l < NLEV; ++l) {
        float4 v = lb[(size_t)l * 131072 + idx];
        s.x += v.x; s.y += v.y; s.z += v.z; s.w += v.w;
    }
    reinterpret_cast<float4*>(out)[idx] = s;
}

extern "C" void kernel_launch(void* const* d_in, const int* in_sizes, int n_in,
                              void* d_out, int out_size, void* d_ws, size_t ws_size,
                              hipStream_t stream) {
    const float* x   = (const float*)d_in[0];
    const float* w1s = (const float*)d_in[1];
    const float* b1s = (const float*)d_in[2];
    const float* w2s = (const float*)d_in[3];
    const float* b2s = (const float*)d_in[4];
    float* out = (float*)d_out;

    float* pw            = (float*)d_ws;                          // 64 KB
    int* pc              = (int*)(pw + T_TOKENS * NLEV);          // 8 KB
    int* order           = pc + T_TOKENS;                         // 8 KB
    unsigned* units      = (unsigned*)(order + T_TOKENS);         // 2 KB
    int* ucount          = (int*)(units + MAXU);                  // 4 B
    unsigned short* xbf  = (unsigned short*)((char*)d_ws + (256 << 10));  // 1 MB
    float* lvlbuf        = (float*)((char*)d_ws + (2 << 20));     // 16 MB

    route_kernel<<<T_TOKENS / 4, 256, 0, stream>>>(x, w1s, b1s, pw, pc, xbf);
    sort_kernel<<<1, 256, 0, stream>>>(pc, order, units, ucount);
    out_kernel<<<2 * MAXU, 256, 0, stream>>>(xbf, w2s, b2s, pw, order, units, ucount, lvlbuf);
    reduce_kernel<<<512, 256, 0, stream>>>(lvlbuf, out);
}